// Round 5
// baseline (104.117 us; speedup 1.0000x reference)
//
#include <hip/hip_runtime.h>

// Problem constants (from reference)
#define B 1024
#define R 256
#define D 512
#define G 4

#define LOG2E 1.44269504088896340736f

// Workspace layout (float offsets). Total = 1,445,888 floats = 5.8 MB.
// PB: per (r, chunk-of-4-d): [th(4) | fa(4) | q0(4) | q1(4) | q2(4) | q3(4)] (24 floats, 96 B)
//   fa = -kappa*tanh(isp)*LOG2E ;  t = (x - th)*fa ;  sigmoid = 1/(1+exp2(t))
//   qg = sigmoid(ml)*tanh(esp)*softmax(A)_g
#define OFF_PB   0                       // [R][128][24]
#define OFF_EPI  (R*128*24)              // [R][16]  {offe0..3, gm0..3, k8e, hw, pad...}
#define OFF_XT   (OFF_EPI + R*16)        // [D][B]   x transposed
#define OFF_PART (OFF_XT + D*B)          // [128][B] per-r-pair partial of y

typedef float f2 __attribute__((ext_vector_type(2)));
static __device__ __forceinline__ f2 mk2(float a, float b) { f2 v; v.x = a; v.y = b; return v; }
static __device__ __forceinline__ f2 mk2s(float a) { return mk2(a, a); }

__device__ __forceinline__ float sig_precise(float v) {
    return 1.0f / (1.0f + expf(-v));
}

// ---------------- Kernel 0: transpose x -> xT[d][b] ----------------
__global__ __launch_bounds__(256)
void sge_transpose(const float* __restrict__ x, float* __restrict__ xT)
{
    __shared__ float t[64][65];
    const int tid = threadIdx.x, tx = tid & 63, ty = tid >> 6;
    const int d0 = blockIdx.x * 64, b0 = blockIdx.y * 64;
    #pragma unroll
    for (int i = 0; i < 64; i += 4)
        t[ty + i][tx] = x[(size_t)(b0 + ty + i) * D + d0 + tx];
    __syncthreads();
    #pragma unroll
    for (int i = 0; i < 64; i += 4)
        xT[(size_t)(d0 + ty + i) * B + b0 + tx] = t[tx][ty + i];
}

// ---------------- Kernel 1: fold all b-independent math ----------------
__global__ __launch_bounds__(256)
void sge_precompute(const float* __restrict__ th,  const float* __restrict__ isp,
                    const float* __restrict__ esp, const float* __restrict__ ml,
                    const float* __restrict__ lk,  const float* __restrict__ gl,
                    const float* __restrict__ tg,  const float* __restrict__ gml,
                    const float* __restrict__ kf,  const float* __restrict__ hw,
                    float* __restrict__ ws)
{
    const int r   = blockIdx.x;
    const int tid = threadIdx.x;
    __shared__ float4 red[256];

    float kappa = expf(lk[0]);
    kappa = fminf(fmaxf(kappa, 0.5f), 50.0f);

    float4 psum = make_float4(0.f, 0.f, 0.f, 0.f);
    for (int d = tid; d < D; d += 256) {
        const int idx = r * D + d;
        const float thv  = th[idx];
        const float ineq = tanhf(isp[idx]);
        const float es   = tanhf(esp[idx]);
        const float mm   = sig_precise(ml[idx]);
        // softmax over g (axis 0) of group_logits[:, d]
        const float g0 = gl[0*D + d], g1 = gl[1*D + d], g2 = gl[2*D + d], g3 = gl[3*D + d];
        const float mx = fmaxf(fmaxf(g0, g1), fmaxf(g2, g3));
        const float e0 = expf(g0 - mx), e1 = expf(g1 - mx), e2 = expf(g2 - mx), e3 = expf(g3 - mx);
        const float inv = 1.0f / (e0 + e1 + e2 + e3);
        const float a0 = e0 * inv, a1 = e1 * inv, a2 = e2 * inv, a3 = e3 * inv;

        const float fa = -kappa * ineq * LOG2E;
        const float s  = mm * es;
        const float s0 = s * a0, s1 = s * a1, s2 = s * a2, s3 = s * a3;

        const int chunk = d >> 2, j = d & 3;
        float* pc = ws + OFF_PB + ((size_t)r * 128 + chunk) * 24;
        pc[j]      = thv;
        pc[4 + j]  = fa;
        pc[8 + j]  = s0;
        pc[12 + j] = s1;
        pc[16 + j] = s2;
        pc[20 + j] = s3;
        psum.x += s0; psum.y += s1; psum.z += s2; psum.w += s3;
    }
    red[tid] = psum;
    __syncthreads();
    for (int s = 128; s > 0; s >>= 1) {
        if (tid < s) {
            red[tid].x += red[tid + s].x;
            red[tid].y += red[tid + s].y;
            red[tid].z += red[tid + s].z;
            red[tid].w += red[tid + s].w;
        }
        __syncthreads();
    }
    if (tid == 0) {
        const float4 base = red[0];
        const float gm0 = sig_precise(gml[r * G + 0]);
        const float gm1 = sig_precise(gml[r * G + 1]);
        const float gm2 = sig_precise(gml[r * G + 2]);
        const float gm3 = sig_precise(gml[r * G + 3]);
        const float en  = gm0 + gm1 + gm2 + gm3 + 1e-6f;
        const float k   = sig_precise(kf[r]) * en;
        float* epi = ws + OFF_EPI + r * 16;
        epi[0] = 6.0f * (base.x + tg[r * G + 0]) * LOG2E;
        epi[1] = 6.0f * (base.y + tg[r * G + 1]) * LOG2E;
        epi[2] = 6.0f * (base.z + tg[r * G + 2]) * LOG2E;
        epi[3] = 6.0f * (base.w + tg[r * G + 3]) * LOG2E;
        epi[4] = gm0; epi[5] = gm1; epi[6] = gm2; epi[7] = gm3;
        epi[8] = 8.0f * k * LOG2E;
        epi[9] = hw[r];
        epi[10] = 0.f; epi[11] = 0.f; epi[12] = 0.f;
        epi[13] = 0.f; epi[14] = 0.f; epi[15] = 0.f;
    }
}

// ---------------- Kernel 2: the 134M-element hot loop (LDS-free) ----------------
// Block: 512 thr = 8 waves = 2 r × 4 d-quarters. Wave: 1 r × 128 b (lane = b-pair)
// × 128 d. x read coalesced from xT (f2/lane); params as broadcast VMEM loads into
// VGPRs (forced vector address). Single vmcnt counter, in-order -> distance-1 A/B
// prefetch actually pipelines. No LDS/barriers until the final merge.
__global__ __launch_bounds__(512, 4)
void sge_main(const float* __restrict__ ws, float* __restrict__ part)
{
    __shared__ float lds1[6][64][8];
    __shared__ float lds2[64][2];

    const int tid  = threadIdx.x;
    const int lane = tid & 63;
    const int w    = __builtin_amdgcn_readfirstlane(tid >> 6);
    const int dq   = w & 3;        // d-quarter 0..3
    const int rl   = w >> 2;       // 0..1
    const int bt   = blockIdx.x;   // 0..7   (128 b each)
    const int rg   = blockIdx.y;   // 0..127 (2 r each)
    const int r    = rg * 2 + rl;

    const int b0 = bt * 128 + 2 * lane;
    const float* xcol = ws + OFF_XT + (size_t)(dq * 128) * B + b0;

    // param base for this wave's 32 chunks; force the address into a VGPR so the
    // compiler emits global_load (broadcast) instead of s_load (out-of-order SMEM).
    int pbyte = (int)(((size_t)r * 128 + (size_t)dq * 32) * 24 * 4);
    asm volatile("" : "+v"(pbyte));
    const char* pbase = (const char*)ws + pbyte;

    f2 acc0 = mk2s(0.f), acc1 = mk2s(0.f), acc2 = mk2s(0.f), acc3 = mk2s(0.f);

    float pA[24], pB[24];
    f2 xA[4], xB[4];

    auto loadP = [&](float (&p)[24], int c) {
        const float4* q = reinterpret_cast<const float4*>(pbase + (size_t)c * 96);
        #pragma unroll
        for (int k = 0; k < 6; ++k) {
            const float4 v = q[k];
            p[4*k+0] = v.x; p[4*k+1] = v.y; p[4*k+2] = v.z; p[4*k+3] = v.w;
        }
    };
    auto loadX = [&](f2 (&xv)[4], int c) {
        #pragma unroll
        for (int j = 0; j < 4; ++j)
            xv[j] = *reinterpret_cast<const f2*>(xcol + (size_t)(c * 4 + j) * B);
    };
    auto compute = [&](const float (&p)[24], const f2 (&xv)[4]) {
        #pragma unroll
        for (int j = 0; j < 4; ++j) {
            const f2 t = (xv[j] - mk2s(p[j])) * mk2s(p[4 + j]);   // v_pk_sub / v_pk_mul
            f2 q;
            q.x = __builtin_amdgcn_exp2f(t.x);
            q.y = __builtin_amdgcn_exp2f(t.y);
            const f2 a = q + 1.0f;
            const float rp = __builtin_amdgcn_rcpf(a.x * a.y);    // one rcp per b-pair
            const f2 c2 = mk2(a.y * rp, a.x * rp);                // sigmoid pair
            acc0 = __builtin_elementwise_fma(mk2s(p[8  + j]), c2, acc0);
            acc1 = __builtin_elementwise_fma(mk2s(p[12 + j]), c2, acc1);
            acc2 = __builtin_elementwise_fma(mk2s(p[16 + j]), c2, acc2);
            acc3 = __builtin_elementwise_fma(mk2s(p[20 + j]), c2, acc3);
        }
    };

    loadP(pA, 0); loadX(xA, 0);
    #pragma unroll 1
    for (int c = 0; c < 32; c += 2) {
        loadP(pB, c + 1); loadX(xB, c + 1);
        compute(pA, xA);
        const int cn = (c + 2 < 32) ? (c + 2) : 0;   // tail prefetch dead but harmless
        loadP(pA, cn); loadX(xA, cn);
        compute(pB, xB);
    }

    // ---- merge d-quarters within the block (the only barriers in this kernel) ----
    if (dq > 0) {
        float* s = &lds1[rl * 3 + dq - 1][lane][0];
        s[0] = acc0.x; s[1] = acc0.y; s[2] = acc1.x; s[3] = acc1.y;
        s[4] = acc2.x; s[5] = acc2.y; s[6] = acc3.x; s[7] = acc3.y;
    }
    __syncthreads();

    f2 contrib = mk2s(0.f);
    if (dq == 0) {
        #pragma unroll
        for (int k = 0; k < 3; ++k) {
            const float* s = &lds1[rl * 3 + k][lane][0];
            acc0 += mk2(s[0], s[1]);
            acc1 += mk2(s[2], s[3]);
            acc2 += mk2(s[4], s[5]);
            acc3 += mk2(s[6], s[7]);
        }
        const float* epi = ws + OFF_EPI + r * 16;
        const float C12 = -12.0f * LOG2E;
        const float C8  = -8.0f  * LOG2E;
        auto sigmoid2 = [&](f2 t) {
            f2 q;
            q.x = __builtin_amdgcn_exp2f(t.x);
            q.y = __builtin_amdgcn_exp2f(t.y);
            const f2 a = q + 1.0f;
            const float rp = __builtin_amdgcn_rcpf(a.x * a.y);
            return mk2(a.y * rp, a.x * rp);
        };
        const f2 pg0 = sigmoid2(__builtin_elementwise_fma(acc0, mk2s(C12), mk2s(epi[0])));
        const f2 pg1 = sigmoid2(__builtin_elementwise_fma(acc1, mk2s(C12), mk2s(epi[1])));
        const f2 pg2 = sigmoid2(__builtin_elementwise_fma(acc2, mk2s(C12), mk2s(epi[2])));
        const f2 pg3 = sigmoid2(__builtin_elementwise_fma(acc3, mk2s(C12), mk2s(epi[3])));
        f2 score = pg0 * mk2s(epi[4]);
        score = __builtin_elementwise_fma(pg1, mk2s(epi[5]), score);
        score = __builtin_elementwise_fma(pg2, mk2s(epi[6]), score);
        score = __builtin_elementwise_fma(pg3, mk2s(epi[7]), score);
        const f2 z = sigmoid2(__builtin_elementwise_fma(score, mk2s(C8), mk2s(epi[8])));
        contrib = mk2s(epi[9]) * z;   // hw[r] * z
    }
    if (w == 4) { lds2[lane][0] = contrib.x; lds2[lane][1] = contrib.y; }
    __syncthreads();
    if (w == 0) {
        const f2 tot = contrib + mk2(lds2[lane][0], lds2[lane][1]);
        *reinterpret_cast<f2*>(part + (size_t)rg * B + b0) = tot;
    }
}

// ---------------- Kernel 3: deterministic final reduction ----------------
__global__ __launch_bounds__(256)
void sge_finalize(const float* __restrict__ part, const float* __restrict__ hb,
                  float* __restrict__ y)
{
    const int b = blockIdx.x * 256 + threadIdx.x;
    float s = hb[0];
    #pragma unroll 8
    for (int k = 0; k < 128; ++k) s += part[(size_t)k * B + b];
    y[b] = s;
}

extern "C" void kernel_launch(void* const* d_in, const int* in_sizes, int n_in,
                              void* d_out, int out_size, void* d_ws, size_t ws_size,
                              hipStream_t stream)
{
    const float* x   = (const float*)d_in[0];
    const float* th  = (const float*)d_in[1];
    const float* isp = (const float*)d_in[2];
    const float* esp = (const float*)d_in[3];
    const float* ml  = (const float*)d_in[4];
    const float* lk  = (const float*)d_in[5];
    const float* gl  = (const float*)d_in[6];
    const float* tg  = (const float*)d_in[7];
    const float* gml = (const float*)d_in[8];
    const float* kf  = (const float*)d_in[9];
    const float* hw  = (const float*)d_in[10];
    const float* hb  = (const float*)d_in[11];
    float* ws = (float*)d_ws;
    float* y  = (float*)d_out;

    sge_transpose<<<dim3(D / 64, B / 64), 256, 0, stream>>>(x, ws + OFF_XT);
    sge_precompute<<<R, 256, 0, stream>>>(th, isp, esp, ml, lk, gl, tg, gml, kf, hw, ws);
    sge_main<<<dim3(8, 128), 512, 0, stream>>>(ws, ws + OFF_PART);
    sge_finalize<<<B / 256, 256, 0, stream>>>(ws + OFF_PART, hb, y);
}

// Round 6
// 70.372 us; speedup vs baseline: 1.4795x; 1.4795x over previous
//
#include <hip/hip_runtime.h>

// Problem constants (from reference)
#define B 1024
#define R 256
#define D 512
#define G 4

#define LOG2E 1.44269504088896340736f

// Workspace layout (float offsets). Total = 855,040 floats = 3.42 MB.
// PB: per (r, chunk-of-8-d) interleaved params: [th(8) | fa(8) | q0(8) | q1(8) | q2(8) | q3(8)]
//   fa = -kappa*tanh(isp)*LOG2E ;  t = (x - th)*fa ;  sigmoid = 1/(1+exp2(t))
//   qg = sigmoid(ml)*tanh(esp)*softmax(A)_g
#define OFF_PB   0                       // [R][64][48]
#define OFF_EPI  (R*64*48)               // [R][12]  {offe0..3, gm0..3, k8e, hw, pad, pad}
#define OFF_PART (OFF_EPI + R*12)        // [64][B]  per-(rg,dhalf) partial of y
#define NBG 16                           // b-groups (64 b per block)

typedef float f2 __attribute__((ext_vector_type(2)));
static __device__ __forceinline__ f2 mk2(float a, float b) { f2 v; v.x = a; v.y = b; return v; }

__device__ __forceinline__ float sig_precise(float v) {
    return 1.0f / (1.0f + expf(-v));
}

// ---------------- Kernel 1: fold all b-independent math ----------------
__global__ __launch_bounds__(256)
void sge_precompute(const float* __restrict__ th,  const float* __restrict__ isp,
                    const float* __restrict__ esp, const float* __restrict__ ml,
                    const float* __restrict__ lk,  const float* __restrict__ gl,
                    const float* __restrict__ tg,  const float* __restrict__ gml,
                    const float* __restrict__ kf,  const float* __restrict__ hw,
                    float* __restrict__ ws)
{
    const int r   = blockIdx.x;
    const int tid = threadIdx.x;
    __shared__ float4 red[256];

    float kappa = expf(lk[0]);
    kappa = fminf(fmaxf(kappa, 0.5f), 50.0f);

    float4 psum = make_float4(0.f, 0.f, 0.f, 0.f);
    for (int d = tid; d < D; d += 256) {
        const int idx = r * D + d;
        const float thv  = th[idx];
        const float ineq = tanhf(isp[idx]);
        const float es   = tanhf(esp[idx]);
        const float mm   = sig_precise(ml[idx]);
        // softmax over g (axis 0) of group_logits[:, d]
        const float g0 = gl[0*D + d], g1 = gl[1*D + d], g2 = gl[2*D + d], g3 = gl[3*D + d];
        const float mx = fmaxf(fmaxf(g0, g1), fmaxf(g2, g3));
        const float e0 = expf(g0 - mx), e1 = expf(g1 - mx), e2 = expf(g2 - mx), e3 = expf(g3 - mx);
        const float inv = 1.0f / (e0 + e1 + e2 + e3);
        const float a0 = e0 * inv, a1 = e1 * inv, a2 = e2 * inv, a3 = e3 * inv;

        const float fa = -kappa * ineq * LOG2E;   // exp2((x-th)*fa) == exp(-kappa*ineq*(x-th))
        const float s  = mm * es;
        const float s0 = s * a0, s1 = s * a1, s2 = s * a2, s3 = s * a3;

        const int chunk = d >> 3, j = d & 7;
        float* pc = ws + OFF_PB + (size_t)(r * 64 + chunk) * 48;
        pc[j]      = thv;
        pc[8 + j]  = fa;
        pc[16 + j] = s0;
        pc[24 + j] = s1;
        pc[32 + j] = s2;
        pc[40 + j] = s3;
        psum.x += s0; psum.y += s1; psum.z += s2; psum.w += s3;
    }
    red[tid] = psum;
    __syncthreads();
    for (int s = 128; s > 0; s >>= 1) {
        if (tid < s) {
            red[tid].x += red[tid + s].x;
            red[tid].y += red[tid + s].y;
            red[tid].z += red[tid + s].z;
            red[tid].w += red[tid + s].w;
        }
        __syncthreads();
    }
    if (tid == 0) {
        const float4 base = red[0];
        const float gm0 = sig_precise(gml[r * G + 0]);
        const float gm1 = sig_precise(gml[r * G + 1]);
        const float gm2 = sig_precise(gml[r * G + 2]);
        const float gm3 = sig_precise(gml[r * G + 3]);
        const float en  = gm0 + gm1 + gm2 + gm3 + 1e-6f;
        const float k   = sig_precise(kf[r]) * en;
        float* epi = ws + OFF_EPI + r * 12;
        epi[0] = 6.0f * (base.x + tg[r * G + 0]) * LOG2E;
        epi[1] = 6.0f * (base.y + tg[r * G + 1]) * LOG2E;
        epi[2] = 6.0f * (base.z + tg[r * G + 2]) * LOG2E;
        epi[3] = 6.0f * (base.w + tg[r * G + 3]) * LOG2E;
        epi[4] = gm0; epi[5] = gm1; epi[6] = gm2; epi[7] = gm3;
        epi[8] = 8.0f * k * LOG2E;
        epi[9] = hw[r];
        epi[10] = 0.f; epi[11] = 0.f;
    }
}

// ---------------- Kernel 2: the 134M-element hot loop ----------------
// Grid: 16 b-groups x (32 r-groups x 2 d-halves) = 1024 blocks = exactly full
// machine at 4 blocks/CU (8 waves/SIMD). Block: 512 thr = 8 waves; wave w owns
// r = rg*8+w for 64 b's (lane = b) over 256 d (this block's d-half), staged in
// LDS as two 128-d quarters (xl 33.8 KB -> thread-capped occupancy, not LDS).
// Params: wave-uniform s_load chunks (48 fp32, A/B distance-1 in SGPRs).
// Compute: packed-f32 over natural d-pairs (every pk op has <=1 SGPR-pair src),
// pairwise rcp (1.5 trans/elem).
__global__ __launch_bounds__(512, 8)
void sge_main(const float* __restrict__ x, const float* __restrict__ ws,
              float* __restrict__ part)
{
    __shared__ float xl[64 * 132];   // 64 b rows x 128 d, pitch 132 (bank-floor-optimal)
    __shared__ float zbuf[512];

    const int tid  = threadIdx.x;
    const int lane = tid & 63;
    const int w    = __builtin_amdgcn_readfirstlane(tid >> 6);  // force wave-uniform
    const int bg   = blockIdx.x;          // 0..15
    const int rgdh = blockIdx.y;          // 0..63
    const int rg   = rgdh >> 1;           // 0..31
    const int dh   = rgdh & 1;            // d-half 0..1
    const int r    = rg * 8 + w;

    const float* pb = ws + OFF_PB + (size_t)r * (64 * 48);

    f2 acc0 = mk2(0.f, 0.f), acc1 = mk2(0.f, 0.f), acc2 = mk2(0.f, 0.f), acc3 = mk2(0.f, 0.f);

    float pA[48], pB[48];
    float4 xaA, xbA, xaB, xbB;

    auto compute = [&](const float (&p)[48], const float4& xa, const float4& xb) {
        const float xs[8] = {xa.x, xa.y, xa.z, xa.w, xb.x, xb.y, xb.z, xb.w};
        #pragma unroll
        for (int i = 0; i < 4; ++i) {
            const f2 xp  = mk2(xs[2*i],     xs[2*i + 1]);
            const f2 th2 = mk2(p[2*i],      p[2*i + 1]);
            const f2 fa2 = mk2(p[8 + 2*i],  p[9 + 2*i]);
            const f2 t   = (xp - th2) * fa2;            // v_pk_sub / v_pk_mul, 1 SGPR-pair each
            f2 q;
            q.x = __builtin_amdgcn_exp2f(t.x);
            q.y = __builtin_amdgcn_exp2f(t.y);
            const f2 a = q + 1.0f;                      // v_pk_add (inline const)
            const float rp = __builtin_amdgcn_rcpf(a.x * a.y);   // one rcp per d-pair
            const f2 c = mk2(a.y * rp, a.x * rp);       // sigmoid pair
            acc0 = __builtin_elementwise_fma(mk2(p[16 + 2*i], p[17 + 2*i]), c, acc0);
            acc1 = __builtin_elementwise_fma(mk2(p[24 + 2*i], p[25 + 2*i]), c, acc1);
            acc2 = __builtin_elementwise_fma(mk2(p[32 + 2*i], p[33 + 2*i]), c, acc2);
            acc3 = __builtin_elementwise_fma(mk2(p[40 + 2*i], p[41 + 2*i]), c, acc3);
        }
    };

    for (int qtr = 0; qtr < 2; ++qtr) {
        const int doff = dh * 256 + qtr * 128;   // global d offset of this quarter
        __syncthreads();   // all waves done with previous quarter before overwrite
        // stage 64 rows x 128 d (as float4), fully coalesced: 2048 f4 / 512 thr
        for (int i = tid; i < 64 * 32; i += 512) {
            const int row = i >> 5, c4 = i & 31;
            const float4 v = *reinterpret_cast<const float4*>(
                &x[(size_t)(bg * 64 + row) * D + doff + c4 * 4]);
            *reinterpret_cast<float4*>(&xl[row * 132 + c4 * 4]) = v;
        }
        __syncthreads();

        const int cb = dh * 32 + qtr * 16;   // param chunk base (8 d per chunk)
        // prologue: load chunk 0 of this quarter
        {
            const float* pc = pb + (size_t)cb * 48;
            #pragma unroll
            for (int j = 0; j < 48; ++j) pA[j] = pc[j];
            xaA = *reinterpret_cast<const float4*>(&xl[lane * 132 + 0]);
            xbA = *reinterpret_cast<const float4*>(&xl[lane * 132 + 4]);
        }
        #pragma unroll 1
        for (int c = 0; c < 16; c += 2) {
            // prefetch chunk c+1 while computing chunk c
            {
                const float* pc = pb + (size_t)(cb + c + 1) * 48;
                #pragma unroll
                for (int j = 0; j < 48; ++j) pB[j] = pc[j];
                xaB = *reinterpret_cast<const float4*>(&xl[lane * 132 + (c + 1) * 8]);
                xbB = *reinterpret_cast<const float4*>(&xl[lane * 132 + (c + 1) * 8 + 4]);
            }
            compute(pA, xaA, xbA);
            // prefetch chunk c+2 (tail prefetch clamped; dead but harmless)
            {
                const int cn = (c + 2 < 16) ? (c + 2) : 0;
                const float* pc = pb + (size_t)(cb + cn) * 48;
                #pragma unroll
                for (int j = 0; j < 48; ++j) pA[j] = pc[j];
                xaA = *reinterpret_cast<const float4*>(&xl[lane * 132 + cn * 8]);
                xbA = *reinterpret_cast<const float4*>(&xl[lane * 132 + cn * 8 + 4]);
            }
            compute(pB, xaB, xbB);
        }
    }

    const float a0 = acc0.x + acc0.y;
    const float a1 = acc1.x + acc1.y;
    const float a2 = acc2.x + acc2.y;
    const float a3 = acc3.x + acc3.y;

    // partial epilogue: this block only has half the d-range; the nonlinear part
    // (pg/score/z) needs the FULL acc over d. So write raw acc partials instead?
    // No: acc is a d-sum; the two d-halves' accs must be added BEFORE the sigmoid.
    // part layout: [64][B] holds per (rg,dh) RAW acc contributions? That would need
    // 4 accs per (b,r). Instead: pair up the two d-halves via workspace: each block
    // writes acc4 to a [rg][dh][8wave][64lane][4] buffer and dh==? -- simpler:
    // keep nonlinearity here is WRONG. We write raw accs and finalize does the
    // nonlinear chain per (b,r). See sge_acc/sge_finalize below.
    // (acc write replaces the old zbuf epilogue)
    {
        // part here is reinterpreted as [32 rg][2 dh][8 w][16 bg][64 lane][4]
        float* pa = part + ((((size_t)rg * 2 + dh) * 8 + w) * 16 + bg) * 64 * 4 + lane * 4;
        pa[0] = a0; pa[1] = a1; pa[2] = a2; pa[3] = a3;
    }
    (void)zbuf;
}

// ---------------- Kernel 3: combine d-halves, nonlinear chain, reduce r ----------------
// Grid: 16 bg blocks x 256 thr; thread = 4 b's? Layout: each block handles 64 b
// (one bg), 256 threads = 64 lanes x 4 r-slices; loop r within slice; LDS-reduce.
__global__ __launch_bounds__(256)
void sge_finalize(const float* __restrict__ part, const float* __restrict__ ws,
                  const float* __restrict__ hb, float* __restrict__ y)
{
    __shared__ float red[256];
    const int tid  = threadIdx.x;
    const int lane = tid & 63;        // b within group
    const int slice = tid >> 6;       // 0..3 (r-slices of 64)
    const int bg   = blockIdx.x;      // 0..15
    const float C12 = -12.0f * LOG2E;
    const float C8  = -8.0f  * LOG2E;

    float s = 0.f;
    for (int rr = 0; rr < 64; ++rr) {
        const int r  = slice * 64 + rr;
        const int rg = r >> 3, w = r & 7;
        const float* p0 = part + ((((size_t)rg * 2 + 0) * 8 + w) * 16 + bg) * 64 * 4 + lane * 4;
        const float* p1 = part + ((((size_t)rg * 2 + 1) * 8 + w) * 16 + bg) * 64 * 4 + lane * 4;
        const float a0 = p0[0] + p1[0];
        const float a1 = p0[1] + p1[1];
        const float a2 = p0[2] + p1[2];
        const float a3 = p0[3] + p1[3];
        const float* epi = ws + OFF_EPI + r * 12;
        const float pg0 = __builtin_amdgcn_rcpf(1.0f + __builtin_amdgcn_exp2f(fmaf(C12, a0, epi[0])));
        const float pg1 = __builtin_amdgcn_rcpf(1.0f + __builtin_amdgcn_exp2f(fmaf(C12, a1, epi[1])));
        const float pg2 = __builtin_amdgcn_rcpf(1.0f + __builtin_amdgcn_exp2f(fmaf(C12, a2, epi[2])));
        const float pg3 = __builtin_amdgcn_rcpf(1.0f + __builtin_amdgcn_exp2f(fmaf(C12, a3, epi[3])));
        float score = pg0 * epi[4];
        score = fmaf(pg1, epi[5], score);
        score = fmaf(pg2, epi[6], score);
        score = fmaf(pg3, epi[7], score);
        const float z = __builtin_amdgcn_rcpf(1.0f + __builtin_amdgcn_exp2f(fmaf(C8, score, epi[8])));
        s = fmaf(epi[9], z, s);
    }
    red[tid] = s;
    __syncthreads();
    if (slice == 0) {
        const float tot = hb[0] + red[lane] + red[64 + lane] + red[128 + lane] + red[192 + lane];
        y[bg * 64 + lane] = tot;
    }
}

extern "C" void kernel_launch(void* const* d_in, const int* in_sizes, int n_in,
                              void* d_out, int out_size, void* d_ws, size_t ws_size,
                              hipStream_t stream)
{
    const float* x   = (const float*)d_in[0];
    const float* th  = (const float*)d_in[1];
    const float* isp = (const float*)d_in[2];
    const float* esp = (const float*)d_in[3];
    const float* ml  = (const float*)d_in[4];
    const float* lk  = (const float*)d_in[5];
    const float* gl  = (const float*)d_in[6];
    const float* tg  = (const float*)d_in[7];
    const float* gml = (const float*)d_in[8];
    const float* kf  = (const float*)d_in[9];
    const float* hw  = (const float*)d_in[10];
    const float* hb  = (const float*)d_in[11];
    float* ws = (float*)d_ws;
    float* y  = (float*)d_out;

    sge_precompute<<<R, 256, 0, stream>>>(th, isp, esp, ml, lk, gl, tg, gml, kf, hw, ws);
    sge_main<<<dim3(NBG, 64), 512, 0, stream>>>(x, ws, ws + OFF_PART);
    sge_finalize<<<NBG, 256, 0, stream>>>(ws + OFF_PART, ws, hb, y);
}